// Round 27
// baseline (140.116 us; speedup 1.0000x reference)
//
#include <hip/hip_runtime.h>
#include <hip/hip_cooperative_groups.h>
namespace cg = cooperative_groups;

typedef _Float16 f16x8 __attribute__((ext_vector_type(8)));
typedef _Float16 f16x4 __attribute__((ext_vector_type(4)));
typedef _Float16 f16x2 __attribute__((ext_vector_type(2)));
typedef float    f32x4 __attribute__((ext_vector_type(4)));

#define NPTS   385
#define GLMIN  (-6.0f)
#define INVH   32.0f
#define NVIRT  (170 * NPTS)

__device__ unsigned g_tab[2 * 170 * 5 * NPTS];   // f16x2 (o0,o1) curves, 2.62 MB

// ---- global ws layout (halfword units) ----
#define PRE_OFF   0
#define PRE_SZ    (2 * 170 * 64)
#define W1G_OFF   (PRE_OFF + PRE_SZ)          // 21760
#define W2P_OFF   (W1G_OFF + 2 * 64)          // 21888
#define W3P_OFF   (W2P_OFF + 2 * 32 * 64)     // 25984
#define WFR_OFF   (W3P_OFF + 2 * 16 * 32)     // 27008
#define H16_END   (WFR_OFF + 320)             // 27328
#define FOFF      H16_END
#define B2P_F     0
#define B3P_F     (B2P_F + 2 * 32)

// ---- LDS (phase-2 fragments) ----
#define L_W1    0
#define L_W2    128
#define L_W3    (L_W2 + 64 * 72)              // 4736
#define L_WFR   (L_W3 + 32 * 40)              // 6016
#define L_END   (L_WFR + 10 * 40)             // 6416 hw

__device__ __forceinline__ f16x8 hfma8(f16x8 a, f16x8 b, f16x8 c) {
    return __builtin_elementwise_fma(a, b, c);
}
__device__ __forceinline__ f16x8 hrelu8(f16x8 a) {
    const f16x8 z = {0, 0, 0, 0, 0, 0, 0, 0};
    return __builtin_elementwise_max(a, z);
}
__device__ __forceinline__ f16x4 hrelu4(f16x4 a) {
    const f16x4 z = {0, 0, 0, 0};
    return __builtin_elementwise_max(a, z);
}
__device__ __forceinline__ f16x2 pkrtz(float a, float b) {
    return __builtin_bit_cast(f16x2, __builtin_amdgcn_cvt_pkrtz(a, b));
}

// Round-27: r26's three stages fused into ONE cooperative kernel.
// Budget analysis (r23/r26): main+gap=11.9, pre~1.5, build~2 => ~15us of the
// 32.3 is per-kernel launch/boundary overhead (~5us/kernel). grid.sync()
// replaces the two kernel boundaries. 512 blocks x 512 thr = exactly 2
// blocks/CU co-resident (<=128 VGPR via waves_per_eu(4,4), 23.6 KB LDS).
__global__ __launch_bounds__(512)
__attribute__((amdgpu_waves_per_eu(4, 4)))
void fused_all(const float* __restrict__ feat, const float* __restrict__ emb,
               const float* __restrict__ W1a, const float* __restrict__ b1a,
               const float* __restrict__ W2a, const float* __restrict__ b2a,
               const float* __restrict__ W3a, const float* __restrict__ b3a,
               const float* __restrict__ W1b, const float* __restrict__ b1b,
               const float* __restrict__ W2b, const float* __restrict__ b2b,
               const float* __restrict__ W3b, const float* __restrict__ b3b,
               const float* __restrict__ Wf, const float* __restrict__ bf,
               _Float16* __restrict__ ws16, float2* __restrict__ out, int nB)
{
    __shared__ float sW1[2550];
    __shared__ float sE[52];
    __shared__ __align__(16) _Float16 sm16[L_END];
    __shared__ __align__(16) float    smf[96];

    cg::grid_group grid = cg::this_grid();
    const int tid = threadIdx.x;

    // ================= phase 1: pre-table + fragment tables -> ws =================
    if (blockIdx.x < 342) {
        const int team = (blockIdx.x >= 171) ? 1 : 0;
        const int bx   = blockIdx.x - team * 171;
        const float* __restrict__ W1 = team ? W1b : W1a;
        const float* __restrict__ B1 = team ? b1b : b1a;
        const float* __restrict__ W2 = team ? W2b : W2a;
        const float* __restrict__ B2 = team ? b2b : b2a;
        const float* __restrict__ W3 = team ? W3b : W3a;
        const float* __restrict__ B3 = team ? b3b : b3a;
        float* __restrict__ wsf = (float*)(ws16 + FOFF);

        if (bx < 170) {
            const int cc = bx;
            for (int i = tid; i < 2550; i += 512) sW1[i] = W1[i];
            for (int i = tid; i < 50; i += 512)   sE[i]  = emb[cc * 50 + i];
            __syncthreads();
            if (tid < 64) {
                const int k = tid;
                float v = 0.0f;
                if (k < 50) {
                    v = B1[k];
                    const float* __restrict__ wr = sW1 + k * 51;
                    #pragma unroll 5
                    for (int d = 0; d < 50; ++d)
                        v = fmaf(wr[d], sE[d], v);
                }
                ws16[PRE_OFF + team * 170 * 64 + cc * 64 + k] =
                    (_Float16)((k < 50) ? v : 0.0f);
            }
        } else {
            for (int i = tid; i < 64; i += 512)
                ws16[W1G_OFF + team * 64 + i] =
                    (_Float16)((i < 50) ? W1[i * 51 + 50] : 0.0f);
            for (int i = tid; i < 32 * 64; i += 512) {
                const int m = i >> 6, k = i & 63;
                ws16[W2P_OFF + team * 2048 + i] =
                    (_Float16)((m < 25 && k < 50) ? W2[m * 50 + k] : 0.0f);
            }
            for (int i = tid; i < 16 * 32; i += 512) {
                const int t = i >> 5, m = i & 31;
                ws16[W3P_OFF + team * 512 + i] =
                    (_Float16)((t < 10 && m < 25) ? W3[t * 25 + m] : 0.0f);
            }
            for (int i = tid; i < 5 * 2 * 16; i += 512) {
                const int s = i >> 5, r = (i >> 4) & 1, k = i & 15;
                ws16[WFR_OFF + team * 160 + i] =
                    (_Float16)((k < 10) ? Wf[r * 100 + team * 50 + s * 10 + k] : 0.0f);
            }
            for (int i = tid; i < 32; i += 512)
                wsf[B2P_F + team * 32 + i] = (i < 25) ? B2[i] : 0.0f;
            for (int i = tid; i < 16; i += 512)
                wsf[B3P_F + team * 16 + i] = (i < 10) ? B3[i] : 0.0f;
        }
    }

    grid.sync();

    // ================= phase 2: MFMA table build =================
    {
        for (int i = tid; i < 16; i += 512)
            *(f16x8*)(sm16 + L_W1 + i * 8) = *(const f16x8*)(ws16 + W1G_OFF + i * 8);
        for (int i = tid; i < 64 * 8; i += 512) {
            const int r = i >> 3, ch = i & 7;
            *(f16x8*)(sm16 + L_W2 + r * 72 + ch * 8) =
                *(const f16x8*)(ws16 + W2P_OFF + r * 64 + ch * 8);
        }
        for (int i = tid; i < 32 * 4; i += 512) {
            const int r = i >> 2, ch = i & 3;
            *(f16x8*)(sm16 + L_W3 + r * 40 + ch * 8) =
                *(const f16x8*)(ws16 + W3P_OFF + r * 32 + ch * 8);
        }
        for (int i = tid; i < 40; i += 512) {
            const int ts = i >> 2, ch = i & 3;
            *(f16x8*)(sm16 + L_WFR + ts * 40 + ch * 8) =
                *(const f16x8*)(ws16 + WFR_OFF + ts * 32 + ch * 8);
        }
        for (int i = tid; i < 24; i += 512)
            *(f32x4*)(smf + i * 4) =
                *(const f32x4*)((const float*)(ws16 + FOFF) + i * 4);
        __syncthreads();

        const int l  = tid & 63;
        const int c  = l & 15;
        const int g  = l >> 4;
        const int wv = tid >> 6;

        #pragma clang loop unroll(disable)
        for (int w = blockIdx.x; w < 1024; w += gridDim.x) {
            const int team = w >> 9;
            const int vblk = w & 511;

            const int v = (vblk * 8 + wv) * 16 + c;
            const bool valid = v < NVIRT;
            const int vE = valid ? v : (NVIRT - 1);
            const int champ = vE / NPTS, ip = vE - champ * NPTS;
            const float gl = GLMIN + (float)ip * (1.0f / INVH);

            f16x8 w2A[2][2];
            #pragma unroll
            for (int mt = 0; mt < 2; ++mt)
                #pragma unroll
                for (int kf = 0; kf < 2; ++kf)
                    w2A[mt][kf] = *(const f16x8*)(sm16 + L_W2
                                     + (team * 32 + mt * 16 + c) * 72 + kf * 32 + g * 8);
            const f16x4 w3A0 = *(const f16x4*)(sm16 + L_W3 + (team * 16 + c) * 40 + 4 * g);
            const f16x4 w3A1 = *(const f16x4*)(sm16 + L_W3 + (team * 16 + c) * 40 + 16 + 4 * g);
            const f16x8 w1gA = *(const f16x8*)(sm16 + L_W1 + team * 64 + g * 8);
            const f16x8 w1gB = *(const f16x8*)(sm16 + L_W1 + team * 64 + 32 + g * 8);
            const f32x4 b2lo = *(const f32x4*)(smf + B2P_F + team * 32 + 4 * g);
            const f32x4 b2hi = *(const f32x4*)(smf + B2P_F + team * 32 + 16 + 4 * g);
            const f32x4 b3v  = *(const f32x4*)(smf + B3P_F + team * 16 + 4 * g);
            f16x4 wfrAll = {0, 0, 0, 0};
            if (c < 10)
                wfrAll = *(const f16x4*)(sm16 + L_WFR + (team * 5 + (c >> 1)) * 40
                                         + (c & 1) * 16 + 4 * g);

            const _Float16 glh = (_Float16)gl;
            const f16x8 glv = {glh, glh, glh, glh, glh, glh, glh, glh};
            const f32x4 zero4 = {0.f, 0.f, 0.f, 0.f};

            const _Float16* __restrict__ prow =
                ws16 + PRE_OFF + (team * 170 + champ) * 64;
            const f16x8 pc0 = *(const f16x8*)(prow + g * 8);
            const f16x8 pc1 = *(const f16x8*)(prow + 32 + g * 8);

            const f16x8 h10 = hrelu8(hfma8(w1gA, glv, pc0));
            const f16x8 h11 = hrelu8(hfma8(w1gB, glv, pc1));

            f32x4 a0  = __builtin_amdgcn_mfma_f32_16x16x32_f16(w2A[0][0], h10, b2lo,  0, 0, 0);
            f32x4 a0x = __builtin_amdgcn_mfma_f32_16x16x32_f16(w2A[0][1], h11, zero4, 0, 0, 0);
            f32x4 a1  = __builtin_amdgcn_mfma_f32_16x16x32_f16(w2A[1][0], h10, b2hi,  0, 0, 0);
            f32x4 a1x = __builtin_amdgcn_mfma_f32_16x16x32_f16(w2A[1][1], h11, zero4, 0, 0, 0);
            a0 = a0 + a0x;
            a1 = a1 + a1x;

            const f16x2 p00 = pkrtz(a0[0], a0[1]);
            const f16x2 p01 = pkrtz(a0[2], a0[3]);
            const f16x2 p10 = pkrtz(a1[0], a1[1]);
            const f16x2 p11 = pkrtz(a1[2], a1[3]);
            const f16x4 b3t0 = hrelu4((f16x4){p00.x, p00.y, p01.x, p01.y});
            const f16x4 b3t1 = hrelu4((f16x4){p10.x, p10.y, p11.x, p11.y});

            f32x4 a3  = __builtin_amdgcn_mfma_f32_16x16x16f16(w3A0, b3t0, b3v,   0, 0, 0);
            f32x4 a3x = __builtin_amdgcn_mfma_f32_16x16x16f16(w3A1, b3t1, zero4, 0, 0, 0);
            a3 = a3 + a3x;

            const f16x2 q0 = pkrtz(a3[0], a3[1]);
            const f16x2 q1 = pkrtz(a3[2], a3[3]);
            const f16x4 h3f = hrelu4((f16x4){q0.x, q0.y, q1.x, q1.y});

            const f32x4 a4 = __builtin_amdgcn_mfma_f32_16x16x16f16(wfrAll, h3f, zero4, 0, 0, 0);

            if (valid && g <= 2) {
                const int ebase = (team * 170 + champ) * 5;
                f16x2 pA;
                pA.x = (_Float16)a4[0];
                pA.y = (_Float16)a4[1];
                g_tab[(ebase + 2 * g) * NPTS + ip] = __builtin_bit_cast(unsigned, pA);
                if (g <= 1) {
                    f16x2 pB;
                    pB.x = (_Float16)a4[2];
                    pB.y = (_Float16)a4[3];
                    g_tab[(ebase + 2 * g + 1) * NPTS + ip] = __builtin_bit_cast(unsigned, pB);
                }
            }
        }
    }

    grid.sync();

    // ================= phase 3: per-sample table lookup =================
    const float bf0 = bf[0], bf1 = bf[1];
    for (int s = blockIdx.x * 512 + tid; s < nB; s += gridDim.x * 512) {
        const float4* f4 = reinterpret_cast<const float4*>(feat + (size_t)s * 12);
        const float4 v0 = f4[0], v1 = f4[1], v2 = f4[2];
        const float fr_[12] = {v0.x, v0.y, v0.z, v0.w, v1.x, v1.y, v1.z, v1.w,
                               v2.x, v2.y, v2.z, v2.w};

        int   iT[2];
        float fT[2];
        #pragma unroll
        for (int team = 0; team < 2; ++team) {
            const float u = (fr_[team] - GLMIN) * INVH;
            int i = (int)u;
            i = (i < 0) ? 0 : ((i > NPTS - 2) ? NPTS - 2 : i);
            float f = u - (float)i;
            f = fminf(fmaxf(f, 0.0f), 1.0f);
            iT[team] = i;
            fT[team] = f;
        }

        float o0 = bf0, o1 = bf1;
        #pragma unroll
        for (int sl = 0; sl < 10; ++sl) {
            const int team = sl / 5;
            const int ci = (int)fr_[2 + sl];
            const unsigned* __restrict__ p =
                g_tab + ((team * 170 + ci) * 5 + (sl - team * 5)) * NPTS + iT[team];
            const f16x2 ha = __builtin_bit_cast(f16x2, p[0]);
            const f16x2 hb = __builtin_bit_cast(f16x2, p[1]);
            const float a0 = (float)ha.x, a1 = (float)ha.y;
            const float b0 = (float)hb.x, b1 = (float)hb.y;
            o0 += fmaf(fT[team], b0 - a0, a0);
            o1 += fmaf(fT[team], b1 - a1, a1);
        }
        out[s] = make_float2(o0, o1);
    }
}

// ---------------- r26 fallback kernels (launched if cooperative fails) -------
__global__ void precompute(const float* __restrict__ emb,
                           const float* __restrict__ W1a, const float* __restrict__ b1a,
                           const float* __restrict__ W2a, const float* __restrict__ b2a,
                           const float* __restrict__ W3a, const float* __restrict__ b3a,
                           const float* __restrict__ W1b, const float* __restrict__ b1b,
                           const float* __restrict__ W2b, const float* __restrict__ b2b,
                           const float* __restrict__ W3b, const float* __restrict__ b3b,
                           const float* __restrict__ Wf,
                           _Float16* __restrict__ ws16)
{
    __shared__ float sW1[2550];
    __shared__ float sE[52];
    const int team = blockIdx.y;
    const float* __restrict__ W1 = team ? W1b : W1a;
    const float* __restrict__ B1 = team ? b1b : b1a;
    const float* __restrict__ W2 = team ? W2b : W2a;
    const float* __restrict__ B2 = team ? b2b : b2a;
    const float* __restrict__ W3 = team ? W3b : W3a;
    const float* __restrict__ B3 = team ? b3b : b3a;
    float* __restrict__ wsf = (float*)(ws16 + FOFF);
    const int tid = threadIdx.x;

    if (blockIdx.x < 170) {
        const int cc = blockIdx.x;
        for (int i = tid; i < 2550; i += 64) sW1[i] = W1[i];
        for (int i = tid; i < 50; i += 64)   sE[i]  = emb[cc * 50 + i];
        __syncthreads();
        const int k = tid;
        float v = 0.0f;
        if (k < 50) {
            v = B1[k];
            const float* __restrict__ wr = sW1 + k * 51;
            #pragma unroll 5
            for (int d = 0; d < 50; ++d)
                v = fmaf(wr[d], sE[d], v);
        }
        ws16[PRE_OFF + team * 170 * 64 + cc * 64 + k] = (_Float16)((k < 50) ? v : 0.0f);
    } else {
        for (int i = tid; i < 64; i += 64)
            ws16[W1G_OFF + team * 64 + i] = (_Float16)((i < 50) ? W1[i * 51 + 50] : 0.0f);
        for (int i = tid; i < 32 * 64; i += 64) {
            const int m = i >> 6, k = i & 63;
            ws16[W2P_OFF + team * 2048 + i] =
                (_Float16)((m < 25 && k < 50) ? W2[m * 50 + k] : 0.0f);
        }
        for (int i = tid; i < 16 * 32; i += 64) {
            const int t = i >> 5, m = i & 31;
            ws16[W3P_OFF + team * 512 + i] =
                (_Float16)((t < 10 && m < 25) ? W3[t * 25 + m] : 0.0f);
        }
        for (int i = tid; i < 5 * 2 * 16; i += 64) {
            const int s = i >> 5, r = (i >> 4) & 1, k = i & 15;
            ws16[WFR_OFF + team * 160 + i] =
                (_Float16)((k < 10) ? Wf[r * 100 + team * 50 + s * 10 + k] : 0.0f);
        }
        for (int i = tid; i < 32; i += 64) wsf[B2P_F + team * 32 + i] = (i < 25) ? B2[i] : 0.0f;
        for (int i = tid; i < 16; i += 64) wsf[B3P_F + team * 16 + i] = (i < 10) ? B3[i] : 0.0f;
    }
}

__global__ __launch_bounds__(512)
__attribute__((amdgpu_waves_per_eu(4, 4)))
void build_tab_mfma(const _Float16* __restrict__ ws16)
{
    __shared__ __align__(16) _Float16 sm16[L_END];
    __shared__ __align__(16) float    smf[96];

    const int tid = threadIdx.x;
    const int l  = tid & 63;
    const int c  = l & 15;
    const int g  = l >> 4;
    const int wv = tid >> 6;
    const int team = blockIdx.y;

    for (int i = tid; i < 16; i += 512)
        *(f16x8*)(sm16 + L_W1 + i * 8) = *(const f16x8*)(ws16 + W1G_OFF + i * 8);
    for (int i = tid; i < 64 * 8; i += 512) {
        const int r = i >> 3, ch = i & 7;
        *(f16x8*)(sm16 + L_W2 + r * 72 + ch * 8) =
            *(const f16x8*)(ws16 + W2P_OFF + r * 64 + ch * 8);
    }
    for (int i = tid; i < 32 * 4; i += 512) {
        const int r = i >> 2, ch = i & 3;
        *(f16x8*)(sm16 + L_W3 + r * 40 + ch * 8) =
            *(const f16x8*)(ws16 + W3P_OFF + r * 32 + ch * 8);
    }
    for (int i = tid; i < 40; i += 512) {
        const int ts = i >> 2, ch = i & 3;
        *(f16x8*)(sm16 + L_WFR + ts * 40 + ch * 8) =
            *(const f16x8*)(ws16 + WFR_OFF + ts * 32 + ch * 8);
    }
    for (int i = tid; i < 24; i += 512)
        *(f32x4*)(smf + i * 4) = *(const f32x4*)((const float*)(ws16 + FOFF) + i * 4);
    __syncthreads();

    const int v = (blockIdx.x * 8 + wv) * 16 + c;
    const bool valid = v < NVIRT;
    const int vE = valid ? v : (NVIRT - 1);
    const int champ = vE / NPTS, ip = vE - champ * NPTS;
    const float gl = GLMIN + (float)ip * (1.0f / INVH);

    f16x8 w2A[2][2];
    #pragma unroll
    for (int mt = 0; mt < 2; ++mt)
        #pragma unroll
        for (int kf = 0; kf < 2; ++kf)
            w2A[mt][kf] = *(const f16x8*)(sm16 + L_W2
                             + (team * 32 + mt * 16 + c) * 72 + kf * 32 + g * 8);
    const f16x4 w3A0 = *(const f16x4*)(sm16 + L_W3 + (team * 16 + c) * 40 + 4 * g);
    const f16x4 w3A1 = *(const f16x4*)(sm16 + L_W3 + (team * 16 + c) * 40 + 16 + 4 * g);
    const f16x8 w1gA = *(const f16x8*)(sm16 + L_W1 + team * 64 + g * 8);
    const f16x8 w1gB = *(const f16x8*)(sm16 + L_W1 + team * 64 + 32 + g * 8);
    const f32x4 b2lo = *(const f32x4*)(smf + B2P_F + team * 32 + 4 * g);
    const f32x4 b2hi = *(const f32x4*)(smf + B2P_F + team * 32 + 16 + 4 * g);
    const f32x4 b3v  = *(const f32x4*)(smf + B3P_F + team * 16 + 4 * g);
    f16x4 wfrAll = {0, 0, 0, 0};
    if (c < 10)
        wfrAll = *(const f16x4*)(sm16 + L_WFR + (team * 5 + (c >> 1)) * 40
                                 + (c & 1) * 16 + 4 * g);

    const _Float16 glh = (_Float16)gl;
    const f16x8 glv = {glh, glh, glh, glh, glh, glh, glh, glh};
    const f32x4 zero4 = {0.f, 0.f, 0.f, 0.f};

    const _Float16* __restrict__ prow = ws16 + PRE_OFF + (team * 170 + champ) * 64;
    const f16x8 pc0 = *(const f16x8*)(prow + g * 8);
    const f16x8 pc1 = *(const f16x8*)(prow + 32 + g * 8);

    const f16x8 h10 = hrelu8(hfma8(w1gA, glv, pc0));
    const f16x8 h11 = hrelu8(hfma8(w1gB, glv, pc1));

    f32x4 a0  = __builtin_amdgcn_mfma_f32_16x16x32_f16(w2A[0][0], h10, b2lo,  0, 0, 0);
    f32x4 a0x = __builtin_amdgcn_mfma_f32_16x16x32_f16(w2A[0][1], h11, zero4, 0, 0, 0);
    f32x4 a1  = __builtin_amdgcn_mfma_f32_16x16x32_f16(w2A[1][0], h10, b2hi,  0, 0, 0);
    f32x4 a1x = __builtin_amdgcn_mfma_f32_16x16x32_f16(w2A[1][1], h11, zero4, 0, 0, 0);
    a0 = a0 + a0x;
    a1 = a1 + a1x;

    const f16x2 p00 = pkrtz(a0[0], a0[1]);
    const f16x2 p01 = pkrtz(a0[2], a0[3]);
    const f16x2 p10 = pkrtz(a1[0], a1[1]);
    const f16x2 p11 = pkrtz(a1[2], a1[3]);
    const f16x4 b3t0 = hrelu4((f16x4){p00.x, p00.y, p01.x, p01.y});
    const f16x4 b3t1 = hrelu4((f16x4){p10.x, p10.y, p11.x, p11.y});

    f32x4 a3  = __builtin_amdgcn_mfma_f32_16x16x16f16(w3A0, b3t0, b3v,   0, 0, 0);
    f32x4 a3x = __builtin_amdgcn_mfma_f32_16x16x16f16(w3A1, b3t1, zero4, 0, 0, 0);
    a3 = a3 + a3x;

    const f16x2 q0 = pkrtz(a3[0], a3[1]);
    const f16x2 q1 = pkrtz(a3[2], a3[3]);
    const f16x4 h3f = hrelu4((f16x4){q0.x, q0.y, q1.x, q1.y});

    const f32x4 a4 = __builtin_amdgcn_mfma_f32_16x16x16f16(wfrAll, h3f, zero4, 0, 0, 0);

    if (valid && g <= 2) {
        const int ebase = (team * 170 + champ) * 5;
        f16x2 pA;
        pA.x = (_Float16)a4[0];
        pA.y = (_Float16)a4[1];
        g_tab[(ebase + 2 * g) * NPTS + ip] = __builtin_bit_cast(unsigned, pA);
        if (g <= 1) {
            f16x2 pB;
            pB.x = (_Float16)a4[2];
            pB.y = (_Float16)a4[3];
            g_tab[(ebase + 2 * g + 1) * NPTS + ip] = __builtin_bit_cast(unsigned, pB);
        }
    }
}

__global__ __launch_bounds__(256)
void table_main(const float* __restrict__ feat, const float* __restrict__ bf,
                float2* __restrict__ out, int nB)
{
    const int s = blockIdx.x * 256 + threadIdx.x;
    if (s >= nB) return;
    const float4* f4 = reinterpret_cast<const float4*>(feat + (size_t)s * 12);
    const float4 v0 = f4[0], v1 = f4[1], v2 = f4[2];
    const float fr_[12] = {v0.x, v0.y, v0.z, v0.w, v1.x, v1.y, v1.z, v1.w,
                           v2.x, v2.y, v2.z, v2.w};

    int   iT[2];
    float fT[2];
    #pragma unroll
    for (int team = 0; team < 2; ++team) {
        const float u = (fr_[team] - GLMIN) * INVH;
        int i = (int)u;
        i = (i < 0) ? 0 : ((i > NPTS - 2) ? NPTS - 2 : i);
        float f = u - (float)i;
        f = fminf(fmaxf(f, 0.0f), 1.0f);
        iT[team] = i;
        fT[team] = f;
    }

    float o0 = bf[0], o1 = bf[1];
    #pragma unroll
    for (int sl = 0; sl < 10; ++sl) {
        const int team = sl / 5;
        const int ci = (int)fr_[2 + sl];
        const unsigned* __restrict__ p =
            g_tab + ((team * 170 + ci) * 5 + (sl - team * 5)) * NPTS + iT[team];
        const f16x2 ha = __builtin_bit_cast(f16x2, p[0]);
        const f16x2 hb = __builtin_bit_cast(f16x2, p[1]);
        const float a0 = (float)ha.x, a1 = (float)ha.y;
        const float b0 = (float)hb.x, b1 = (float)hb.y;
        o0 += fmaf(fT[team], b0 - a0, a0);
        o1 += fmaf(fT[team], b1 - a1, a1);
    }
    out[s] = make_float2(o0, o1);
}

extern "C" void kernel_launch(void* const* d_in, const int* in_sizes, int n_in,
                              void* d_out, int out_size, void* d_ws, size_t ws_size,
                              hipStream_t stream) {
    const float* feat = (const float*)d_in[0];
    const float* emb  = (const float*)d_in[1];
    const float* W1a  = (const float*)d_in[2];
    const float* b1a  = (const float*)d_in[3];
    const float* W2a  = (const float*)d_in[4];
    const float* b2a  = (const float*)d_in[5];
    const float* W3a  = (const float*)d_in[6];
    const float* b3a  = (const float*)d_in[7];
    const float* W1b  = (const float*)d_in[8];
    const float* b1b  = (const float*)d_in[9];
    const float* W2b  = (const float*)d_in[10];
    const float* b2b  = (const float*)d_in[11];
    const float* W3b  = (const float*)d_in[12];
    const float* b3b  = (const float*)d_in[13];
    const float* Wf   = (const float*)d_in[14];
    const float* bf   = (const float*)d_in[15];
    _Float16* ws16 = (_Float16*)d_ws;
    float2*   out2 = (float2*)d_out;
    int nB = in_sizes[0] / 12;

    void* args[] = {
        (void*)&feat, (void*)&emb,
        (void*)&W1a, (void*)&b1a, (void*)&W2a, (void*)&b2a,
        (void*)&W3a, (void*)&b3a,
        (void*)&W1b, (void*)&b1b, (void*)&W2b, (void*)&b2b,
        (void*)&W3b, (void*)&b3b,
        (void*)&Wf, (void*)&bf, (void*)&ws16, (void*)&out2, (void*)&nB
    };
    hipError_t err = hipLaunchCooperativeKernel(
        (void*)fused_all, dim3(512), dim3(512), args, 0, stream);

    if (err != hipSuccess) {
        // r26 three-kernel fallback (identical output)
        precompute<<<dim3(171, 2), 64, 0, stream>>>(emb,
            W1a, b1a, W2a, b2a, W3a, b3a,
            W1b, b1b, W2b, b2b, W3b, b3b, Wf, ws16);
        const int vblocks = (NVIRT + 127) / 128;
        build_tab_mfma<<<dim3(vblocks, 2), 512, 0, stream>>>(ws16);
        table_main<<<(nB + 255) / 256, 256, 0, stream>>>(feat, bf, out2, nB);
    }
}

// Round 28
// 28.567 us; speedup vs baseline: 4.9048x; 4.9048x over previous
//
#include <hip/hip_runtime.h>

typedef _Float16 f16x8 __attribute__((ext_vector_type(8)));
typedef _Float16 f16x4 __attribute__((ext_vector_type(4)));
typedef _Float16 f16x2 __attribute__((ext_vector_type(2)));
typedef float    f32x4 __attribute__((ext_vector_type(4)));

#define NPTS   385
#define GLMIN  (-6.0f)
#define INVH   32.0f
#define NVIRT  (170 * NPTS)

__device__ unsigned g_tab[2 * 170 * 5 * NPTS];   // f16x2 (o0,o1) curves, 2.62 MB

// ---- build-kernel LDS f16 region (halfword offsets; all rows 16B-aligned) ----
#define L_PRE   0                    // [2][64]   pre-rows for the block's 2 champs
#define L_W1    128                  // [64]      w1 glicko column
#define L_W2    192                  // [32][72]  W2 rows (m<25, k<50; else 0)
#define L_W3    2496                 // [16][40]  W3 rows (t<10, m<25; else 0)
#define L_WFR   3136                 // [5][40]   Wf rows per slot
#define L_END   3336
#define LF_B2   0
#define LF_B3   32                   // smf floats

__device__ __forceinline__ f16x8 hfma8(f16x8 a, f16x8 b, f16x8 c) {
    return __builtin_elementwise_fma(a, b, c);
}
__device__ __forceinline__ f16x8 hrelu8(f16x8 a) {
    const f16x8 z = {0, 0, 0, 0, 0, 0, 0, 0};
    return __builtin_elementwise_max(a, z);
}
__device__ __forceinline__ f16x4 hrelu4(f16x4 a) {
    const f16x4 z = {0, 0, 0, 0};
    return __builtin_elementwise_max(a, z);
}
__device__ __forceinline__ f16x2 pkrtz(float a, float b) {
    return __builtin_bit_cast(f16x2, __builtin_amdgcn_cvt_pkrtz(a, b));
}

// Round-28: precompute folded INTO the table builder (2-kernel pipeline, no
// ws round-trip; d_ws unused). Each block covers 128 consecutive virtual
// samples (<= 2 champs): it stages W1 (10.2 KB fp32) + 2 emb rows, computes
// the 2 pre-rows in LDS, builds all f16 fragment tables from the raw fp32
// weights (~3.3K elems), then runs the r26 MFMA body with pre reads from LDS.
// r27 lesson: grid.sync() costs ~50us -- kernel boundaries (~5us) are the
// cheaper sync. This removes one of them.
__global__ __launch_bounds__(512)
__attribute__((amdgpu_waves_per_eu(4, 4)))
void build_all(const float* __restrict__ emb,
               const float* __restrict__ W1a, const float* __restrict__ b1a,
               const float* __restrict__ W2a, const float* __restrict__ b2a,
               const float* __restrict__ W3a, const float* __restrict__ b3a,
               const float* __restrict__ W1b, const float* __restrict__ b1b,
               const float* __restrict__ W2b, const float* __restrict__ b2b,
               const float* __restrict__ W3b, const float* __restrict__ b3b,
               const float* __restrict__ Wf)
{
    __shared__ float sW1[2550];
    __shared__ float sE[2][52];
    __shared__ __align__(16) _Float16 sm16[L_END];
    __shared__ __align__(16) float    smf[48];

    const int tid = threadIdx.x;
    const int team = blockIdx.y;
    const float* __restrict__ W1 = team ? W1b : W1a;
    const float* __restrict__ B1 = team ? b1b : b1a;
    const float* __restrict__ W2 = team ? W2b : W2a;
    const float* __restrict__ B2 = team ? b2b : b2a;
    const float* __restrict__ W3 = team ? W3b : W3a;
    const float* __restrict__ B3 = team ? b3b : b3a;

    const int vbase = blockIdx.x * 128;
    const int champ_lo = vbase / NPTS;
    const int ch0 = champ_lo;
    const int ch1 = (champ_lo + 1 < 170) ? champ_lo + 1 : 169;

    // ---- stage raw weights -> LDS (all coalesced) ----
    for (int i = tid; i < 2550; i += 512) sW1[i] = W1[i];
    for (int i = tid; i < 100; i += 512) {
        const int cc = i / 50, d = i % 50;
        sE[cc][d] = emb[(cc ? ch1 : ch0) * 50 + d];
    }
    for (int i = tid; i < 64; i += 512)
        sm16[L_W1 + i] = (_Float16)((i < 50) ? W1[i * 51 + 50] : 0.0f);
    for (int i = tid; i < 32 * 64; i += 512) {
        const int m = i >> 6, k = i & 63;
        sm16[L_W2 + m * 72 + k] =
            (_Float16)((m < 25 && k < 50) ? W2[m * 50 + k] : 0.0f);
    }
    for (int i = tid; i < 16 * 32; i += 512) {
        const int t = i >> 5, m = i & 31;
        sm16[L_W3 + t * 40 + m] =
            (_Float16)((t < 10 && m < 25) ? W3[t * 25 + m] : 0.0f);
    }
    for (int i = tid; i < 5 * 32; i += 512) {
        const int s = i >> 5, r = (i >> 4) & 1, k = i & 15;
        sm16[L_WFR + s * 40 + r * 16 + k] =
            (_Float16)((k < 10) ? Wf[r * 100 + team * 50 + s * 10 + k] : 0.0f);
    }
    for (int i = tid; i < 32; i += 512) smf[LF_B2 + i] = (i < 25) ? B2[i] : 0.0f;
    for (int i = tid; i < 16; i += 512) smf[LF_B3 + i] = (i < 10) ? B3[i] : 0.0f;
    __syncthreads();

    // ---- compute the block's 2 pre-rows (fp32 dot -> f16, as before) ----
    for (int i = tid; i < 128; i += 512) {
        const int cc = i >> 6, k = i & 63;
        float v = 0.0f;
        if (k < 50) {
            v = B1[k];
            const float* __restrict__ wr = sW1 + k * 51;
            #pragma unroll 5
            for (int d = 0; d < 50; ++d)
                v = fmaf(wr[d], sE[cc][d], v);
        }
        sm16[L_PRE + cc * 64 + k] = (_Float16)v;
    }
    __syncthreads();

    // ---- r26 MFMA body, pre from LDS ----
    const int l  = tid & 63;
    const int c  = l & 15;
    const int g  = l >> 4;
    const int wv = tid >> 6;

    const int v = vbase + wv * 16 + c;
    const bool valid = v < NVIRT;
    const int vE = valid ? v : (NVIRT - 1);
    const int champ = vE / NPTS, ip = vE - champ * NPTS;
    const int dch = champ - champ_lo;           // 0 or 1
    const float gl = GLMIN + (float)ip * (1.0f / INVH);

    f16x8 w2A[2][2];
    #pragma unroll
    for (int mt = 0; mt < 2; ++mt)
        #pragma unroll
        for (int kf = 0; kf < 2; ++kf)
            w2A[mt][kf] = *(const f16x8*)(sm16 + L_W2 + (mt * 16 + c) * 72
                                          + kf * 32 + g * 8);
    const f16x4 w3A0 = *(const f16x4*)(sm16 + L_W3 + c * 40 + 4 * g);
    const f16x4 w3A1 = *(const f16x4*)(sm16 + L_W3 + c * 40 + 16 + 4 * g);
    const f16x8 w1gA = *(const f16x8*)(sm16 + L_W1 + g * 8);
    const f16x8 w1gB = *(const f16x8*)(sm16 + L_W1 + 32 + g * 8);
    const f32x4 b2lo = *(const f32x4*)(smf + LF_B2 + 4 * g);
    const f32x4 b2hi = *(const f32x4*)(smf + LF_B2 + 16 + 4 * g);
    const f32x4 b3v  = *(const f32x4*)(smf + LF_B3 + 4 * g);
    f16x4 wfrAll = {0, 0, 0, 0};
    if (c < 10)
        wfrAll = *(const f16x4*)(sm16 + L_WFR + (c >> 1) * 40 + (c & 1) * 16 + 4 * g);

    const _Float16 glh = (_Float16)gl;
    const f16x8 glv = {glh, glh, glh, glh, glh, glh, glh, glh};
    const f32x4 zero4 = {0.f, 0.f, 0.f, 0.f};

    const f16x8 pc0 = *(const f16x8*)(sm16 + L_PRE + dch * 64 + g * 8);
    const f16x8 pc1 = *(const f16x8*)(sm16 + L_PRE + dch * 64 + 32 + g * 8);

    const f16x8 h10 = hrelu8(hfma8(w1gA, glv, pc0));
    const f16x8 h11 = hrelu8(hfma8(w1gB, glv, pc1));

    f32x4 a0  = __builtin_amdgcn_mfma_f32_16x16x32_f16(w2A[0][0], h10, b2lo,  0, 0, 0);
    f32x4 a0x = __builtin_amdgcn_mfma_f32_16x16x32_f16(w2A[0][1], h11, zero4, 0, 0, 0);
    f32x4 a1  = __builtin_amdgcn_mfma_f32_16x16x32_f16(w2A[1][0], h10, b2hi,  0, 0, 0);
    f32x4 a1x = __builtin_amdgcn_mfma_f32_16x16x32_f16(w2A[1][1], h11, zero4, 0, 0, 0);
    a0 = a0 + a0x;
    a1 = a1 + a1x;

    const f16x2 p00 = pkrtz(a0[0], a0[1]);
    const f16x2 p01 = pkrtz(a0[2], a0[3]);
    const f16x2 p10 = pkrtz(a1[0], a1[1]);
    const f16x2 p11 = pkrtz(a1[2], a1[3]);
    const f16x4 b3t0 = hrelu4((f16x4){p00.x, p00.y, p01.x, p01.y});
    const f16x4 b3t1 = hrelu4((f16x4){p10.x, p10.y, p11.x, p11.y});

    f32x4 a3  = __builtin_amdgcn_mfma_f32_16x16x16f16(w3A0, b3t0, b3v,   0, 0, 0);
    f32x4 a3x = __builtin_amdgcn_mfma_f32_16x16x16f16(w3A1, b3t1, zero4, 0, 0, 0);
    a3 = a3 + a3x;

    const f16x2 q0 = pkrtz(a3[0], a3[1]);
    const f16x2 q1 = pkrtz(a3[2], a3[3]);
    const f16x4 h3f = hrelu4((f16x4){q0.x, q0.y, q1.x, q1.y});

    const f32x4 a4 = __builtin_amdgcn_mfma_f32_16x16x16f16(wfrAll, h3f, zero4, 0, 0, 0);

    if (valid && g <= 2) {
        const int ebase = (team * 170 + champ) * 5;
        f16x2 pA;
        pA.x = (_Float16)a4[0];
        pA.y = (_Float16)a4[1];
        g_tab[(ebase + 2 * g) * NPTS + ip] = __builtin_bit_cast(unsigned, pA);
        if (g <= 1) {
            f16x2 pB;
            pB.x = (_Float16)a4[2];
            pB.y = (_Float16)a4[3];
            g_tab[(ebase + 2 * g + 1) * NPTS + ip] = __builtin_bit_cast(unsigned, pB);
        }
    }
}

// 1 thread = 1 sample: 10 independent 8B gathers + lerp (r26 verbatim).
__global__ __launch_bounds__(256)
void table_main(const float* __restrict__ feat, const float* __restrict__ bf,
                float2* __restrict__ out, int nB)
{
    const int s = blockIdx.x * 256 + threadIdx.x;
    if (s >= nB) return;
    const float4* f4 = reinterpret_cast<const float4*>(feat + (size_t)s * 12);
    const float4 v0 = f4[0], v1 = f4[1], v2 = f4[2];
    const float fr_[12] = {v0.x, v0.y, v0.z, v0.w, v1.x, v1.y, v1.z, v1.w,
                           v2.x, v2.y, v2.z, v2.w};

    int   iT[2];
    float fT[2];
    #pragma unroll
    for (int team = 0; team < 2; ++team) {
        const float u = (fr_[team] - GLMIN) * INVH;
        int i = (int)u;
        i = (i < 0) ? 0 : ((i > NPTS - 2) ? NPTS - 2 : i);
        float f = u - (float)i;
        f = fminf(fmaxf(f, 0.0f), 1.0f);
        iT[team] = i;
        fT[team] = f;
    }

    float o0 = bf[0], o1 = bf[1];
    #pragma unroll
    for (int sl = 0; sl < 10; ++sl) {
        const int team = sl / 5;
        const int ci = (int)fr_[2 + sl];
        const unsigned* __restrict__ p =
            g_tab + ((team * 170 + ci) * 5 + (sl - team * 5)) * NPTS + iT[team];
        const f16x2 ha = __builtin_bit_cast(f16x2, p[0]);
        const f16x2 hb = __builtin_bit_cast(f16x2, p[1]);
        const float a0 = (float)ha.x, a1 = (float)ha.y;
        const float b0 = (float)hb.x, b1 = (float)hb.y;
        o0 += fmaf(fT[team], b0 - a0, a0);
        o1 += fmaf(fT[team], b1 - a1, a1);
    }
    out[s] = make_float2(o0, o1);
}

extern "C" void kernel_launch(void* const* d_in, const int* in_sizes, int n_in,
                              void* d_out, int out_size, void* d_ws, size_t ws_size,
                              hipStream_t stream) {
    const float* feat = (const float*)d_in[0];
    const float* emb  = (const float*)d_in[1];
    const float* W1a  = (const float*)d_in[2];
    const float* b1a  = (const float*)d_in[3];
    const float* W2a  = (const float*)d_in[4];
    const float* b2a  = (const float*)d_in[5];
    const float* W3a  = (const float*)d_in[6];
    const float* b3a  = (const float*)d_in[7];
    const float* W1b  = (const float*)d_in[8];
    const float* b1b  = (const float*)d_in[9];
    const float* W2b  = (const float*)d_in[10];
    const float* b2b  = (const float*)d_in[11];
    const float* W3b  = (const float*)d_in[12];
    const float* b3b  = (const float*)d_in[13];
    const float* Wf   = (const float*)d_in[14];
    const float* bf   = (const float*)d_in[15];
    const int nB = in_sizes[0] / 12;

    const int vblocks = (NVIRT + 127) / 128;           // 512
    build_all<<<dim3(vblocks, 2), 512, 0, stream>>>(emb,
        W1a, b1a, W2a, b2a, W3a, b3a,
        W1b, b1b, W2b, b2b, W3b, b3b, Wf);

    table_main<<<(nB + 255) / 256, 256, 0, stream>>>(feat, bf, (float2*)d_out, nB);
}

// Round 29
// 24.827 us; speedup vs baseline: 5.6437x; 1.1506x over previous
//
#include <hip/hip_runtime.h>

typedef _Float16 f16x8 __attribute__((ext_vector_type(8)));
typedef _Float16 f16x4 __attribute__((ext_vector_type(4)));
typedef _Float16 f16x2 __attribute__((ext_vector_type(2)));
typedef float    f32x4 __attribute__((ext_vector_type(4)));

#define NPTS   385
#define GLMIN  (-6.0f)
#define INVH   32.0f
#define NVIRT  (170 * NPTS)

__device__ unsigned g_tab[2 * 170 * 5 * NPTS];   // f16x2 (o0,o1) curves, 2.62 MB

// ---- build-kernel LDS f16 region (halfword offsets) ----
#define L_PRE   0                    // [3][64]   pre-rows for the block's champs
#define L_W1    192                  // [64]
#define L_W2    256                  // [32][72]
#define L_W3    2560                 // [16][40]
#define L_WFR   3200                 // [5][40]
#define L_END   3400
#define LF_B2   0
#define LF_B3   32

__device__ __forceinline__ f16x8 hfma8(f16x8 a, f16x8 b, f16x8 c) {
    return __builtin_elementwise_fma(a, b, c);
}
__device__ __forceinline__ f16x8 hrelu8(f16x8 a) {
    const f16x8 z = {0, 0, 0, 0, 0, 0, 0, 0};
    return __builtin_elementwise_max(a, z);
}
__device__ __forceinline__ f16x4 hrelu4(f16x4 a) {
    const f16x4 z = {0, 0, 0, 0};
    return __builtin_elementwise_max(a, z);
}
__device__ __forceinline__ f16x2 pkrtz(float a, float b) {
    return __builtin_bit_cast(f16x2, __builtin_amdgcn_cvt_pkrtz(a, b));
}

// Round-29: r28's builder with 4x staging amortization. Grid 1024 -> 256
// blocks (128 x 2 teams, all co-resident); each block stages W1/fragments
// ONCE, computes 3 pre-rows (a 512-point span covers <= 3 champs), then
// loops 4 chunks of 128 virtual points through the unchanged MFMA body.
// (r28 budget: build+gap ~16us with a 4:1 staging:compute ratio per block --
// same per-block amortization disease r12 fixed in the old main kernel.)
__global__ __launch_bounds__(512)
__attribute__((amdgpu_waves_per_eu(4, 4)))
void build_all(const float* __restrict__ emb,
               const float* __restrict__ W1a, const float* __restrict__ b1a,
               const float* __restrict__ W2a, const float* __restrict__ b2a,
               const float* __restrict__ W3a, const float* __restrict__ b3a,
               const float* __restrict__ W1b, const float* __restrict__ b1b,
               const float* __restrict__ W2b, const float* __restrict__ b2b,
               const float* __restrict__ W3b, const float* __restrict__ b3b,
               const float* __restrict__ Wf)
{
    __shared__ float sW1[2550];
    __shared__ float sE[3][52];
    __shared__ __align__(16) _Float16 sm16[L_END];
    __shared__ __align__(16) float    smf[48];

    const int tid = threadIdx.x;
    const int team = blockIdx.y;
    const float* __restrict__ W1 = team ? W1b : W1a;
    const float* __restrict__ B1 = team ? b1b : b1a;
    const float* __restrict__ W2 = team ? W2b : W2a;
    const float* __restrict__ B2 = team ? b2b : b2a;
    const float* __restrict__ W3 = team ? W3b : W3a;
    const float* __restrict__ B3 = team ? b3b : b3a;

    const int vbase = blockIdx.x * 512;
    const int champ_lo = vbase / NPTS;

    // ---- stage raw weights -> LDS (coalesced), once per block ----
    for (int i = tid; i < 2550; i += 512) sW1[i] = W1[i];
    for (int i = tid; i < 3 * 50; i += 512) {
        const int cc = i / 50, d = i % 50;
        int ch = champ_lo + cc;
        if (ch > 169) ch = 169;
        sE[cc][d] = emb[ch * 50 + d];
    }
    for (int i = tid; i < 64; i += 512)
        sm16[L_W1 + i] = (_Float16)((i < 50) ? W1[i * 51 + 50] : 0.0f);
    for (int i = tid; i < 32 * 64; i += 512) {
        const int m = i >> 6, k = i & 63;
        sm16[L_W2 + m * 72 + k] =
            (_Float16)((m < 25 && k < 50) ? W2[m * 50 + k] : 0.0f);
    }
    for (int i = tid; i < 16 * 32; i += 512) {
        const int t = i >> 5, m = i & 31;
        sm16[L_W3 + t * 40 + m] =
            (_Float16)((t < 10 && m < 25) ? W3[t * 25 + m] : 0.0f);
    }
    for (int i = tid; i < 5 * 32; i += 512) {
        const int s = i >> 5, r = (i >> 4) & 1, k = i & 15;
        sm16[L_WFR + s * 40 + r * 16 + k] =
            (_Float16)((k < 10) ? Wf[r * 100 + team * 50 + s * 10 + k] : 0.0f);
    }
    for (int i = tid; i < 32; i += 512) smf[LF_B2 + i] = (i < 25) ? B2[i] : 0.0f;
    for (int i = tid; i < 16; i += 512) smf[LF_B3 + i] = (i < 10) ? B3[i] : 0.0f;
    __syncthreads();

    // ---- 3 pre-rows (fp32 dot -> f16) ----
    for (int i = tid; i < 192; i += 512) {
        const int cc = i >> 6, k = i & 63;
        float v = 0.0f;
        if (k < 50) {
            v = B1[k];
            const float* __restrict__ wr = sW1 + k * 51;
            #pragma unroll 5
            for (int d = 0; d < 50; ++d)
                v = fmaf(wr[d], sE[cc][d], v);
        }
        sm16[L_PRE + cc * 64 + k] = (_Float16)v;
    }
    __syncthreads();

    // ---- per-wave invariant fragments ----
    const int l  = tid & 63;
    const int c  = l & 15;
    const int g  = l >> 4;
    const int wv = tid >> 6;

    f16x8 w2A[2][2];
    #pragma unroll
    for (int mt = 0; mt < 2; ++mt)
        #pragma unroll
        for (int kf = 0; kf < 2; ++kf)
            w2A[mt][kf] = *(const f16x8*)(sm16 + L_W2 + (mt * 16 + c) * 72
                                          + kf * 32 + g * 8);
    const f16x4 w3A0 = *(const f16x4*)(sm16 + L_W3 + c * 40 + 4 * g);
    const f16x4 w3A1 = *(const f16x4*)(sm16 + L_W3 + c * 40 + 16 + 4 * g);
    const f16x8 w1gA = *(const f16x8*)(sm16 + L_W1 + g * 8);
    const f16x8 w1gB = *(const f16x8*)(sm16 + L_W1 + 32 + g * 8);
    const f32x4 b2lo = *(const f32x4*)(smf + LF_B2 + 4 * g);
    const f32x4 b2hi = *(const f32x4*)(smf + LF_B2 + 16 + 4 * g);
    const f32x4 b3v  = *(const f32x4*)(smf + LF_B3 + 4 * g);
    f16x4 wfrAll = {0, 0, 0, 0};
    if (c < 10)
        wfrAll = *(const f16x4*)(sm16 + L_WFR + (c >> 1) * 40 + (c & 1) * 16 + 4 * g);
    const f32x4 zero4 = {0.f, 0.f, 0.f, 0.f};

    // ---- 4 chunks of 128 virtual points through the MFMA body ----
    #pragma clang loop unroll(disable)
    for (int ck = 0; ck < 4; ++ck) {
        const int v = vbase + ck * 128 + wv * 16 + c;
        const bool valid = v < NVIRT;
        const int vE = valid ? v : (NVIRT - 1);
        const int champ = vE / NPTS, ip = vE - champ * NPTS;
        const int dch = champ - champ_lo;       // 0..2 within the block's span
        const float gl = GLMIN + (float)ip * (1.0f / INVH);

        const _Float16 glh = (_Float16)gl;
        const f16x8 glv = {glh, glh, glh, glh, glh, glh, glh, glh};

        const f16x8 pc0 = *(const f16x8*)(sm16 + L_PRE + dch * 64 + g * 8);
        const f16x8 pc1 = *(const f16x8*)(sm16 + L_PRE + dch * 64 + 32 + g * 8);

        const f16x8 h10 = hrelu8(hfma8(w1gA, glv, pc0));
        const f16x8 h11 = hrelu8(hfma8(w1gB, glv, pc1));

        f32x4 a0  = __builtin_amdgcn_mfma_f32_16x16x32_f16(w2A[0][0], h10, b2lo,  0, 0, 0);
        f32x4 a0x = __builtin_amdgcn_mfma_f32_16x16x32_f16(w2A[0][1], h11, zero4, 0, 0, 0);
        f32x4 a1  = __builtin_amdgcn_mfma_f32_16x16x32_f16(w2A[1][0], h10, b2hi,  0, 0, 0);
        f32x4 a1x = __builtin_amdgcn_mfma_f32_16x16x32_f16(w2A[1][1], h11, zero4, 0, 0, 0);
        a0 = a0 + a0x;
        a1 = a1 + a1x;

        const f16x2 p00 = pkrtz(a0[0], a0[1]);
        const f16x2 p01 = pkrtz(a0[2], a0[3]);
        const f16x2 p10 = pkrtz(a1[0], a1[1]);
        const f16x2 p11 = pkrtz(a1[2], a1[3]);
        const f16x4 b3t0 = hrelu4((f16x4){p00.x, p00.y, p01.x, p01.y});
        const f16x4 b3t1 = hrelu4((f16x4){p10.x, p10.y, p11.x, p11.y});

        f32x4 a3  = __builtin_amdgcn_mfma_f32_16x16x16f16(w3A0, b3t0, b3v,   0, 0, 0);
        f32x4 a3x = __builtin_amdgcn_mfma_f32_16x16x16f16(w3A1, b3t1, zero4, 0, 0, 0);
        a3 = a3 + a3x;

        const f16x2 q0 = pkrtz(a3[0], a3[1]);
        const f16x2 q1 = pkrtz(a3[2], a3[3]);
        const f16x4 h3f = hrelu4((f16x4){q0.x, q0.y, q1.x, q1.y});

        const f32x4 a4 = __builtin_amdgcn_mfma_f32_16x16x16f16(wfrAll, h3f, zero4, 0, 0, 0);

        if (valid && g <= 2) {
            const int ebase = (team * 170 + champ) * 5;
            f16x2 pA;
            pA.x = (_Float16)a4[0];
            pA.y = (_Float16)a4[1];
            g_tab[(ebase + 2 * g) * NPTS + ip] = __builtin_bit_cast(unsigned, pA);
            if (g <= 1) {
                f16x2 pB;
                pB.x = (_Float16)a4[2];
                pB.y = (_Float16)a4[3];
                g_tab[(ebase + 2 * g + 1) * NPTS + ip] = __builtin_bit_cast(unsigned, pB);
            }
        }
    }
}

// 1 thread = 1 sample: 10 independent 8B gathers + lerp (unchanged).
__global__ __launch_bounds__(256)
void table_main(const float* __restrict__ feat, const float* __restrict__ bf,
                float2* __restrict__ out, int nB)
{
    const int s = blockIdx.x * 256 + threadIdx.x;
    if (s >= nB) return;
    const float4* f4 = reinterpret_cast<const float4*>(feat + (size_t)s * 12);
    const float4 v0 = f4[0], v1 = f4[1], v2 = f4[2];
    const float fr_[12] = {v0.x, v0.y, v0.z, v0.w, v1.x, v1.y, v1.z, v1.w,
                           v2.x, v2.y, v2.z, v2.w};

    int   iT[2];
    float fT[2];
    #pragma unroll
    for (int team = 0; team < 2; ++team) {
        const float u = (fr_[team] - GLMIN) * INVH;
        int i = (int)u;
        i = (i < 0) ? 0 : ((i > NPTS - 2) ? NPTS - 2 : i);
        float f = u - (float)i;
        f = fminf(fmaxf(f, 0.0f), 1.0f);
        iT[team] = i;
        fT[team] = f;
    }

    float o0 = bf[0], o1 = bf[1];
    #pragma unroll
    for (int sl = 0; sl < 10; ++sl) {
        const int team = sl / 5;
        const int ci = (int)fr_[2 + sl];
        const unsigned* __restrict__ p =
            g_tab + ((team * 170 + ci) * 5 + (sl - team * 5)) * NPTS + iT[team];
        const f16x2 ha = __builtin_bit_cast(f16x2, p[0]);
        const f16x2 hb = __builtin_bit_cast(f16x2, p[1]);
        const float a0 = (float)ha.x, a1 = (float)ha.y;
        const float b0 = (float)hb.x, b1 = (float)hb.y;
        o0 += fmaf(fT[team], b0 - a0, a0);
        o1 += fmaf(fT[team], b1 - a1, a1);
    }
    out[s] = make_float2(o0, o1);
}

extern "C" void kernel_launch(void* const* d_in, const int* in_sizes, int n_in,
                              void* d_out, int out_size, void* d_ws, size_t ws_size,
                              hipStream_t stream) {
    const float* feat = (const float*)d_in[0];
    const float* emb  = (const float*)d_in[1];
    const float* W1a  = (const float*)d_in[2];
    const float* b1a  = (const float*)d_in[3];
    const float* W2a  = (const float*)d_in[4];
    const float* b2a  = (const float*)d_in[5];
    const float* W3a  = (const float*)d_in[6];
    const float* b3a  = (const float*)d_in[7];
    const float* W1b  = (const float*)d_in[8];
    const float* b1b  = (const float*)d_in[9];
    const float* W2b  = (const float*)d_in[10];
    const float* b2b  = (const float*)d_in[11];
    const float* W3b  = (const float*)d_in[12];
    const float* b3b  = (const float*)d_in[13];
    const float* Wf   = (const float*)d_in[14];
    const float* bf   = (const float*)d_in[15];
    const int nB = in_sizes[0] / 12;

    const int vblocks = (NVIRT + 511) / 512;           // 128
    build_all<<<dim3(vblocks, 2), 512, 0, stream>>>(emb,
        W1a, b1a, W2a, b2a, W3a, b3a,
        W1b, b1b, W2b, b2b, W3b, b3b, Wf);

    table_main<<<(nB + 255) / 256, 256, 0, stream>>>(feat, bf, (float2*)d_out, nB);
}